// Round 16
// baseline (297.524 us; speedup 1.0000x reference)
//
#include <hip/hip_runtime.h>

// Complex MHA, B=4 S=1024 E=1024 H=16 DH=64.
// pack(fp32->fp16, K-concat complex trick) -> GEMM1 (m201-style 256^2 BK=64,
// 8 waves, 4 quadrant phases/K-tile, front-loaded stage + boundary vmcnt,
// scatter epilogue) -> flash complex attention (swapped 32x32) -> GEMM2 (m97).

typedef _Float16 f16;
typedef _Float16 f16x8 __attribute__((ext_vector_type(8)));
typedef _Float16 f16x4 __attribute__((ext_vector_type(4)));
typedef float f32x4 __attribute__((ext_vector_type(4)));
typedef float f32x16 __attribute__((ext_vector_type(16)));

#define MFMA16(a, b, c) __builtin_amdgcn_mfma_f32_16x16x32_f16(a, b, c, 0, 0, 0)
#define MFMA32(a, b, c) __builtin_amdgcn_mfma_f32_32x32x16_f16(a, b, c, 0, 0, 0)

__device__ inline void load_lds16(const void* g, void* l) {
  __builtin_amdgcn_global_load_lds(
      (const __attribute__((address_space(1))) unsigned int*)g,
      (__attribute__((address_space(3))) unsigned int*)l, 16, 0, 0);
}

__device__ inline unsigned pkrtz(float a, float b) {
  auto t = __builtin_amdgcn_cvt_pkrtz(a, b);
  return __builtin_bit_cast(unsigned, t);
}

// ---------------- pack kernels (fp32 -> fp16, concat layouts) ----------------

__global__ void pack_x_kernel(const float* __restrict__ xr, const float* __restrict__ xi,
                              f16* __restrict__ XC) {
  int i = blockIdx.x * 256 + threadIdx.x;
  if (i >= (4096 * 2048 / 4)) return;
  int idx = i * 4;
  int m = idx >> 11, k = idx & 2047;
  const float* src = (k < 1024) ? (xr + (size_t)m * 1024 + k) : (xi + (size_t)m * 1024 + k - 1024);
  float4 v = *(const float4*)src;
  f16x4 o = {(f16)v.x, (f16)v.y, (f16)v.z, (f16)v.w};
  *(f16x4*)(XC + idx) = o;
}

__global__ void pack_wqkv_kernel(const float* __restrict__ wr, const float* __restrict__ wi,
                                 f16* __restrict__ W) {
  int i = blockIdx.x * 256 + threadIdx.x;
  if (i >= (6144 * 2048 / 4)) return;
  int idx = i * 4;
  int n = idx >> 11, k = idx & 2047;
  const float* base;
  float sgn = 1.f;
  if (n < 3072) {
    if (k < 1024) base = wr + (size_t)n * 1024 + k;
    else { base = wi + (size_t)n * 1024 + k - 1024; sgn = -1.f; }
  } else {
    int n2 = n - 3072;
    if (k < 1024) base = wi + (size_t)n2 * 1024 + k;
    else base = wr + (size_t)n2 * 1024 + k - 1024;
  }
  float4 v = *(const float4*)base;
  f16x4 o = {(f16)(sgn * v.x), (f16)(sgn * v.y), (f16)(sgn * v.z), (f16)(sgn * v.w)};
  *(f16x4*)(W + idx) = o;
}

__global__ void pack_wout_kernel(const float* __restrict__ wor, const float* __restrict__ woi,
                                 f16* __restrict__ W) {
  int i = blockIdx.x * 256 + threadIdx.x;
  if (i >= (2048 * 2048 / 4)) return;
  int idx = i * 4;
  int n = idx >> 11, k = idx & 2047;
  const float* base;
  float sgn = 1.f;
  if (n < 1024) {
    if (k < 1024) base = wor + (size_t)n * 1024 + k;
    else { base = woi + (size_t)n * 1024 + k - 1024; sgn = -1.f; }
  } else {
    int n2 = n - 1024;
    if (k < 1024) base = woi + (size_t)n2 * 1024 + k;
    else base = wor + (size_t)n2 * 1024 + k - 1024;
  }
  float4 v = *(const float4*)base;
  f16x4 o = {(f16)(sgn * v.x), (f16)(sgn * v.y), (f16)(sgn * v.z), (f16)(sgn * v.w)};
  *(f16x4*)(W + idx) = o;
}

struct GemmParams {
  f16 *QC, *KCr, *KCi, *VCT;
  const float *bpr, *bpi;
  float* out;
  const float *bor, *boi;
  int out_complex;
};

// ---------------- GEMM1: 256^2 BK=64, 8 waves, 4 quadrant phases --------------
// C[4096,6144] = A * B^T. Wave (wr,wc): rows wr*128+[0,128), cols wc*64+[0,64).
// LDS: [buf][half][128x64] per operand (128KB). Phase = reads|stage|bar|lgkm|
// MFMA|bar. Stages front-loaded (ph1: A(t+1), ph2: B(t+1)); vmcnt(0) at ph4 end
// (>=2 phases after last issue -> latency covered). Ledger: buf^1 read only
// after every wave's vmcnt(0)+barrier; WAR guarded by prior tile's ph4 barrier.

__global__ __launch_bounds__(512, 1) void gemm1_kernel(const f16* __restrict__ A,
                                                       const f16* __restrict__ B,
                                                       GemmParams p) {
  const int K = 2048;
  __shared__ alignas(16) f16 sA[2][2][8192];
  __shared__ alignas(16) f16 sB[2][2][8192];
  const int tid = threadIdx.x;
  const int w = tid >> 6, l = tid & 63;
  const int lr = l & 15, lk = l >> 4;
  const int lin = blockIdx.x;
  const int xcd = lin & 7, idx = lin >> 3;
  const int mt = idx / 3, ntl = idx % 3;
  const int tm0 = mt * 256;
  const int tn0 = (xcd * 3 + ntl) * 256;
  const int wr = w >> 2, wc = w & 3;
  const int bhB = wc >> 1, wnl = (wc & 1) * 64;

  // staging: per call 512 thr x 16B = 64 rows; row = tid>>3, chunk pre-swizzled
  const int scg = (tid & 7) ^ ((tid >> 3) & 7);
  const f16* gA = A + (size_t)(tm0 + (tid >> 3)) * K + scg * 8;
  const f16* gB = B + (size_t)(tn0 + (tid >> 3)) * K + scg * 8;
  const int dstw = w * 512;

#define SGA(buf, h, j, k0) \
  load_lds16(gA + ((size_t)(h) * 128 + (j) * 64) * K + (size_t)(k0), &sA[buf][h][(j) * 4096 + dstw])
#define SGB(buf, h, j, k0) \
  load_lds16(gB + ((size_t)(h) * 128 + (j) * 64) * K + (size_t)(k0), &sB[buf][h][(j) * 4096 + dstw])

  f32x4 acc[8][4] = {};
  f16x8 af[4][2], bf[4][2];

  SGA(0, 0, 0, 0); SGA(0, 0, 1, 0); SGA(0, 1, 0, 0); SGA(0, 1, 1, 0);
  SGB(0, 0, 0, 0); SGB(0, 0, 1, 0); SGB(0, 1, 0, 0); SGB(0, 1, 1, 0);
  asm volatile("s_waitcnt vmcnt(0)" ::: "memory");
  __builtin_amdgcn_s_barrier();

  for (int t = 0; t < 32; ++t) {
    const int buf = t & 1;
    const int kn = (t + 1) * 64;
    const f16* pA = &sA[buf][wr][0];
    const f16* pB = &sB[buf][bhB][0];

    // ---- ph1: read af(mi0-3)+bf(nj0-1) | stage A(t+1) both halves | Q00 ----
#pragma unroll
    for (int mi = 0; mi < 4; ++mi) {
      int r = mi * 16 + lr;
#pragma unroll
      for (int ks = 0; ks < 2; ++ks)
        af[mi][ks] = *(const f16x8*)&pA[r * 64 + (((ks * 4 + lk) ^ (r & 7)) * 8)];
    }
#pragma unroll
    for (int nj = 0; nj < 2; ++nj) {
      int r = wnl + nj * 16 + lr;
#pragma unroll
      for (int ks = 0; ks < 2; ++ks)
        bf[nj][ks] = *(const f16x8*)&pB[r * 64 + (((ks * 4 + lk) ^ (r & 7)) * 8)];
    }
    if (t < 31) { SGA(buf ^ 1, 0, 0, kn); SGA(buf ^ 1, 0, 1, kn); SGA(buf ^ 1, 1, 0, kn); SGA(buf ^ 1, 1, 1, kn); }
    __builtin_amdgcn_s_barrier();
    asm volatile("s_waitcnt lgkmcnt(0)" ::: "memory");
    __builtin_amdgcn_sched_barrier(0);
    __builtin_amdgcn_s_setprio(1);
#pragma unroll
    for (int mi = 0; mi < 4; ++mi)
#pragma unroll
      for (int nj = 0; nj < 2; ++nj) {
        acc[mi][nj] = MFMA16(af[mi][0], bf[nj][0], acc[mi][nj]);
        acc[mi][nj] = MFMA16(af[mi][1], bf[nj][1], acc[mi][nj]);
      }
    __builtin_amdgcn_s_setprio(0);
    __builtin_amdgcn_s_barrier();

    // ---- ph2: read bf(nj2-3) | stage B(t+1) both halves | Q01 ----
#pragma unroll
    for (int nj = 2; nj < 4; ++nj) {
      int r = wnl + nj * 16 + lr;
#pragma unroll
      for (int ks = 0; ks < 2; ++ks)
        bf[nj][ks] = *(const f16x8*)&pB[r * 64 + (((ks * 4 + lk) ^ (r & 7)) * 8)];
    }
    if (t < 31) { SGB(buf ^ 1, 0, 0, kn); SGB(buf ^ 1, 0, 1, kn); SGB(buf ^ 1, 1, 0, kn); SGB(buf ^ 1, 1, 1, kn); }
    __builtin_amdgcn_s_barrier();
    asm volatile("s_waitcnt lgkmcnt(0)" ::: "memory");
    __builtin_amdgcn_sched_barrier(0);
    __builtin_amdgcn_s_setprio(1);
#pragma unroll
    for (int mi = 0; mi < 4; ++mi)
#pragma unroll
      for (int nj = 2; nj < 4; ++nj) {
        acc[mi][nj] = MFMA16(af[mi][0], bf[nj][0], acc[mi][nj]);
        acc[mi][nj] = MFMA16(af[mi][1], bf[nj][1], acc[mi][nj]);
      }
    __builtin_amdgcn_s_setprio(0);
    __builtin_amdgcn_s_barrier();

    // ---- ph3: read af(mi4-7) | Q10 ----
#pragma unroll
    for (int mi = 0; mi < 4; ++mi) {
      int r = (4 + mi) * 16 + lr;
#pragma unroll
      for (int ks = 0; ks < 2; ++ks)
        af[mi][ks] = *(const f16x8*)&pA[r * 64 + (((ks * 4 + lk) ^ (r & 7)) * 8)];
    }
    __builtin_amdgcn_s_barrier();
    asm volatile("s_waitcnt lgkmcnt(0)" ::: "memory");
    __builtin_amdgcn_sched_barrier(0);
    __builtin_amdgcn_s_setprio(1);
#pragma unroll
    for (int mi = 0; mi < 4; ++mi)
#pragma unroll
      for (int nj = 0; nj < 2; ++nj) {
        acc[4 + mi][nj] = MFMA16(af[mi][0], bf[nj][0], acc[4 + mi][nj]);
        acc[4 + mi][nj] = MFMA16(af[mi][1], bf[nj][1], acc[4 + mi][nj]);
      }
    __builtin_amdgcn_s_setprio(0);
    __builtin_amdgcn_s_barrier();

    // ---- ph4: Q11 | boundary vmcnt(0) (last stage issued 2 phases ago) ----
    __builtin_amdgcn_s_setprio(1);
#pragma unroll
    for (int mi = 0; mi < 4; ++mi)
#pragma unroll
      for (int nj = 2; nj < 4; ++nj) {
        acc[4 + mi][nj] = MFMA16(af[mi][0], bf[nj][0], acc[4 + mi][nj]);
        acc[4 + mi][nj] = MFMA16(af[mi][1], bf[nj][1], acc[4 + mi][nj]);
      }
    __builtin_amdgcn_s_setprio(0);
    if (t < 31) asm volatile("s_waitcnt vmcnt(0)" ::: "memory");
    __builtin_amdgcn_s_barrier();
  }
#undef SGA
#undef SGB

  // ---- scatter epilogue (16x16 C/D: col=lane&15, row=lk*4+r) ----
#pragma unroll
  for (int mi = 0; mi < 8; ++mi)
#pragma unroll
    for (int nj = 0; nj < 4; ++nj) {
      int n = tn0 + wc * 64 + nj * 16 + lr;
      bool im = n >= 3072;
      int nn = im ? n - 3072 : n;
      float bias = im ? p.bpi[nn] : p.bpr[nn];
      int part = nn >> 10;
      int e = nn & 1023, h = e >> 6, dd = e & 63;
      int m0 = tm0 + wr * 128 + mi * 16 + lk * 4;
      int bb = m0 >> 10, s0 = m0 & 1023;
      size_t bh = (size_t)bb * 16 + h;
      if (part == 0) {
#pragma unroll
        for (int r = 0; r < 4; ++r)
          p.QC[(bh * 1024 + s0 + r) * 128 + (im ? 64 : 0) + dd] =
              (f16)((acc[mi][nj][r] + bias) * 0.125f);
      } else if (part == 1) {
#pragma unroll
        for (int r = 0; r < 4; ++r) {
          float v2 = acc[mi][nj][r] + bias;
          size_t o = (bh * 1024 + s0 + r) * 128;
          if (!im) { p.KCr[o + dd] = (f16)v2; p.KCi[o + 64 + dd] = (f16)v2; }
          else     { p.KCr[o + 64 + dd] = (f16)(-v2); p.KCi[o + dd] = (f16)v2; }
        }
      } else {
        f16x4 vv;
#pragma unroll
        for (int r = 0; r < 4; ++r) vv[r] = (f16)(acc[mi][nj][r] + bias);
        *(f16x4*)&p.VCT[((bh * 128 + (im ? 64 : 0) + dd)) * 1024 + s0] = vv;
      }
    }
}

// ---------------- GEMM2 (out proj): m97 128^2, proven 0-conflict --------------

__global__ __launch_bounds__(256) void gemm_out_kernel(const f16* __restrict__ A,
                                                       const f16* __restrict__ B,
                                                       GemmParams p) {
  const int K = 2048;
  __shared__ alignas(16) f16 sA[128 * 64];
  __shared__ alignas(16) f16 sB[128 * 64];
  const int tid = threadIdx.x;
  const int w = tid >> 6, l = tid & 63;
  const int lr = l & 15, lk = l >> 4;
  const int nwg = gridDim.x * gridDim.y;
  const int lin = blockIdx.y * gridDim.x + blockIdx.x;
  const int qq = nwg >> 3, rr = nwg & 7;
  const int xcd = lin & 7, off = lin >> 3;
  const int swz = (xcd < rr ? xcd * (qq + 1) : rr * (qq + 1) + (xcd - rr) * qq) + off;
  const int tm0 = (swz / gridDim.x) * 128;
  const int tn0 = (swz % gridDim.x) * 128;
  const int wm = (w >> 1) * 64, wn = (w & 1) * 64;

  f32x4 acc[4][4] = {};

  for (int k0 = 0; k0 < K; k0 += 64) {
#pragma unroll
    for (int i = 0; i < 4; ++i) {
      int slot = i * 256 + tid;
      int row = slot >> 3;
      int cg = (slot & 7) ^ (row & 7);
      load_lds16(A + (size_t)(tm0 + row) * K + k0 + cg * 8, &sA[(size_t)(i * 256 + (w << 6)) * 8]);
      load_lds16(B + (size_t)(tn0 + row) * K + k0 + cg * 8, &sB[(size_t)(i * 256 + (w << 6)) * 8]);
    }
    __syncthreads();
#pragma unroll
    for (int kk = 0; kk < 2; ++kk) {
      f16x8 af[4], bf[4];
#pragma unroll
      for (int t = 0; t < 4; ++t) {
        int rowA = wm + t * 16 + lr;
        af[t] = *(const f16x8*)&sA[rowA * 64 + ((kk * 4 + lk) ^ (rowA & 7)) * 8];
        int rowB = wn + t * 16 + lr;
        bf[t] = *(const f16x8*)&sB[rowB * 64 + ((kk * 4 + lk) ^ (rowB & 7)) * 8];
      }
#pragma unroll
      for (int mt = 0; mt < 4; ++mt)
#pragma unroll
        for (int nt = 0; nt < 4; ++nt) acc[mt][nt] = MFMA16(af[mt], bf[nt], acc[mt][nt]);
    }
    __syncthreads();
  }

#pragma unroll
  for (int mt = 0; mt < 4; ++mt)
#pragma unroll
    for (int nt = 0; nt < 4; ++nt)
#pragma unroll
      for (int r = 0; r < 4; ++r) {
        int m = tm0 + wm + mt * 16 + lk * 4 + r;
        int n = tn0 + wn + nt * 16 + lr;
        float val = acc[mt][nt][r];
        if (n < 1024) {
          float v2 = val + p.bor[n];
          if (p.out_complex) p.out[((size_t)m * 1024 + n) * 2] = v2;
          else p.out[(size_t)m * 1024 + n] = v2;
        } else {
          if (p.out_complex) p.out[((size_t)m * 1024 + n - 1024) * 2 + 1] = val + p.boi[n - 1024];
        }
      }
}

// ---------------- flash complex attention (swapped-operand 32x32) -------------

__global__ __launch_bounds__(512, 2) void attn_kernel(const f16* __restrict__ QC,
                                                      const f16* __restrict__ KCr,
                                                      const f16* __restrict__ KCi,
                                                      const f16* __restrict__ VCT,
                                                      f16* __restrict__ OC) {
  __shared__ alignas(16) f16 sKr[2][32 * 128];
  __shared__ alignas(16) f16 sKi[2][32 * 128];
  __shared__ alignas(16) f16 sV[2][128 * 32];
  const int tid = threadIdx.x;
  const int w = tid >> 6, l = tid & 63;
  const int lq = l & 31, hi = l >> 5;
  const int bid = blockIdx.x;
  const int xx = bid & 7, yy = bid >> 3;
  const int bh = xx + ((yy >> 2) << 3);
  const int qt = yy & 3;
  const int q0 = qt * 256 + w * 32;
  const f16* Qb = QC + (size_t)bh * 1024 * 128;
  const f16* Krb = KCr + (size_t)bh * 1024 * 128;
  const f16* Kib = KCi + (size_t)bh * 1024 * 128;
  const f16* Vb = VCT + (size_t)bh * 128 * 1024;

  f16x8 qf[8];
#pragma unroll
  for (int c = 0; c < 8; ++c)
    qf[c] = *(const f16x8*)&Qb[(size_t)(q0 + lq) * 128 + c * 16 + hi * 8];

  f32x16 accR[4] = {};
  f32x16 accI[4] = {};
  float m_r = -1e30f, l_r = 0.f, m_i = -1e30f, l_i = 0.f;

  const int sprow = tid >> 3;
  const int cK = (tid & 7) ^ ((tid >> 4) & 7);
  const f16* gKr = Krb + (size_t)(tid >> 4) * 128 + ((tid >> 3) & 1) * 64 + cK * 8;
  const f16* gKi = Kib + (size_t)(tid >> 4) * 128 + ((tid >> 3) & 1) * 64 + cK * 8;
  const int cV = (tid & 7) ^ (sprow & 7);
  const f16* gV = Vb + (size_t)(sprow * 2 + (cV >> 2)) * 1024 + (cV & 3) * 8;
  const int ldsW = w * 512;

#define STAGE(s, k0)                                                 \
  do {                                                               \
    load_lds16(gKr + (size_t)(k0) * 128, &sKr[s][ldsW]);             \
    load_lds16(gKi + (size_t)(k0) * 128, &sKi[s][ldsW]);             \
    load_lds16(gV + (k0), &sV[s][ldsW]);                             \
  } while (0)

  STAGE(0, 0);
  asm volatile("s_waitcnt vmcnt(0)" ::: "memory");
  __syncthreads();
  int cur = 0;

  for (int t = 0; t < 32; ++t) {
    if (t < 31) STAGE(cur ^ 1, (t + 1) * 32);

    f32x16 sr = {}, si = {};
    __builtin_amdgcn_s_setprio(1);
#pragma unroll
    for (int c = 0; c < 8; ++c) {
      int fc = c * 2 + hi;
      int prow = lq * 2 + (fc >> 3);
      int swzc = (fc & 7) ^ (lq & 7);
      f16x8 kr = *(const f16x8*)&sKr[cur][prow * 64 + swzc * 8];
      f16x8 ki = *(const f16x8*)&sKi[cur][prow * 64 + swzc * 8];
      sr = MFMA32(kr, qf[c], sr);
      si = MFMA32(ki, qf[c], si);
    }
    __builtin_amdgcn_s_setprio(0);

    f16x8 prf[2], pif[2];
#pragma unroll
    for (int part = 0; part < 2; ++part) {
      const f32x16& s = part ? si : sr;
      float& m = part ? m_i : m_r;
      float& lsum = part ? l_i : l_r;
      f32x16* acc = part ? accI : accR;
      float vm = s[0];
#pragma unroll
      for (int j = 1; j < 16; ++j) vm = fmaxf(vm, s[j]);
      vm = fmaxf(vm, __shfl_xor(vm, 32));
      if (__any(vm > m + 8.f)) {
        float mn = fmaxf(m, vm);
        float sc = __expf(m - mn);
        lsum *= sc;
#pragma unroll
        for (int a = 0; a < 4; ++a)
#pragma unroll
          for (int j = 0; j < 16; ++j) acc[a][j] *= sc;
        m = mn;
      }
      float p[16];
      float ls = 0.f;
#pragma unroll
      for (int j = 0; j < 16; ++j) { p[j] = __expf(s[j] - m); ls += p[j]; }
      lsum += ls;
      unsigned a0 = pkrtz(p[0], p[1]), b0 = pkrtz(p[4], p[5]);
      unsigned a1 = pkrtz(p[2], p[3]), b1 = pkrtz(p[6], p[7]);
      unsigned a2 = pkrtz(p[8], p[9]), b2 = pkrtz(p[12], p[13]);
      unsigned a3 = pkrtz(p[10], p[11]), b3 = pkrtz(p[14], p[15]);
      asm("v_permlane32_swap_b32 %0, %1" : "+v"(a0), "+v"(b0));
      asm("v_permlane32_swap_b32 %0, %1" : "+v"(a1), "+v"(b1));
      asm("v_permlane32_swap_b32 %0, %1" : "+v"(a2), "+v"(b2));
      asm("v_permlane32_swap_b32 %0, %1" : "+v"(a3), "+v"(b3));
      union { unsigned u[4]; f16x8 v; } f0, f1;
      f0.u[0] = a0; f0.u[1] = a1; f0.u[2] = b0; f0.u[3] = b1;
      f1.u[0] = a2; f1.u[1] = a3; f1.u[2] = b2; f1.u[3] = b3;
      if (part) { pif[0] = f0.v; pif[1] = f1.v; }
      else      { prf[0] = f0.v; prf[1] = f1.v; }
    }

    __builtin_amdgcn_s_setprio(1);
#pragma unroll
    for (int ft = 0; ft < 4; ++ft) {
#pragma unroll
      for (int ks = 0; ks < 2; ++ks) {
        int feat = ft * 32 + lq;
        int prow = feat >> 1;
        int swzc = (((feat & 1) * 4 + ks * 2 + hi) ^ (prow & 7));
        f16x8 vf = *(const f16x8*)&sV[cur][prow * 64 + swzc * 8];
        accR[ft] = MFMA32(vf, prf[ks], accR[ft]);
        accI[ft] = MFMA32(vf, pif[ks], accI[ft]);
      }
    }
    __builtin_amdgcn_s_setprio(0);

    asm volatile("s_waitcnt vmcnt(0)" ::: "memory");
    __syncthreads();
    cur ^= 1;
  }
#undef STAGE

  float lr = l_r + __shfl_xor(l_r, 32);
  float li = l_i + __shfl_xor(l_i, 32);
  float ilr = 1.f / lr, ili = 1.f / li;
  const int bb = bh >> 4, h = bh & 15;
  const int q = q0 + lq;
  f16* rowp = OC + ((size_t)bb * 1024 + q) * 2048 + h * 64;
#pragma unroll
  for (int tt = 0; tt < 2; ++tt) {
#pragma unroll
    for (int g = 0; g < 4; ++g) {
      int d0 = tt * 32 + g * 8 + hi * 4;
      f16x4 ov, oiv;
#pragma unroll
      for (int j = 0; j < 4; ++j) {
        int rg = g * 4 + j;
        float orv = accR[tt][rg] * ilr - accI[tt + 2][rg] * ili;
        float oivv = accR[tt + 2][rg] * ilr + accI[tt][rg] * ili;
        ov[j] = (f16)orv;
        oiv[j] = (f16)oivv;
      }
      *(f16x4*)(rowp + d0) = ov;
      *(f16x4*)(rowp + 1024 + d0) = oiv;
    }
  }
}

// ---------------- launcher ----------------------------------------------------

extern "C" void kernel_launch(void* const* d_in, const int* in_sizes, int n_in,
                              void* d_out, int out_size, void* d_ws, size_t ws_size,
                              hipStream_t stream) {
  const float* xr = (const float*)d_in[0];
  const float* xi = (const float*)d_in[1];
  const float* wpr = (const float*)d_in[2];
  const float* wpi = (const float*)d_in[3];
  const float* bpr = (const float*)d_in[4];
  const float* bpi = (const float*)d_in[5];
  const float* wor = (const float*)d_in[6];
  const float* woi = (const float*)d_in[7];
  const float* bor = (const float*)d_in[8];
  const float* boi = (const float*)d_in[9];

  f16* ws = (f16*)d_ws;
  f16* XC = ws;                       // 4096*2048
  f16* WQKV = XC + 8388608;           // 6144*2048
  f16* QC = WQKV + 12582912;          // 64*1024*128
  f16* KCr = QC + 8388608;
  f16* KCi = KCr + 8388608;
  f16* VCT = KCi + 8388608;           // 64*128*1024
  f16* OC = VCT + 8388608;            // 4096*2048
  f16* WOUT = OC + 8388608;           // 2048*2048

  pack_x_kernel<<<8192, 256, 0, stream>>>(xr, xi, XC);
  pack_wqkv_kernel<<<12288, 256, 0, stream>>>(wpr, wpi, WQKV);
  pack_wout_kernel<<<4096, 256, 0, stream>>>(wor, woi, WOUT);

  GemmParams p1 = {};
  p1.QC = QC; p1.KCr = KCr; p1.KCi = KCi; p1.VCT = VCT;
  p1.bpr = bpr; p1.bpi = bpi;
  // 8 XCD x (16 m-tiles x 3 n-tiles) of 256^2 = 384 blocks
  gemm1_kernel<<<384, 512, 0, stream>>>(XC, WQKV, p1);

  attn_kernel<<<256, 512, 0, stream>>>(QC, KCr, KCi, VCT, OC);

  GemmParams p2 = {};
  p2.out = (float*)d_out; p2.bor = bor; p2.boi = boi;
  p2.out_complex = (out_size == 8388608) ? 1 : 0;
  int ntilesN = p2.out_complex ? 16 : 8;
  gemm_out_kernel<<<dim3(ntilesN, 32), 256, 0, stream>>>(OC, WOUT, p2);
}

// Round 17
// 282.708 us; speedup vs baseline: 1.0524x; 1.0524x over previous
//
#include <hip/hip_runtime.h>

// Complex MHA, B=4 S=1024 E=1024 H=16 DH=64.
// pack(fp32->fp16, K-concat complex trick) -> GEMM1 (R15: 256x128 BK=32 dbuf,
// prefetch-issue-first, 0-conflict layout, 3 blk/CU) -> flash complex attention
// (swapped 32x32, 4-wave QBLK=128, 2 blk/CU) -> GEMM2 (m97 128^2).

typedef _Float16 f16;
typedef _Float16 f16x8 __attribute__((ext_vector_type(8)));
typedef _Float16 f16x4 __attribute__((ext_vector_type(4)));
typedef float f32x4 __attribute__((ext_vector_type(4)));
typedef float f32x16 __attribute__((ext_vector_type(16)));

#define MFMA16(a, b, c) __builtin_amdgcn_mfma_f32_16x16x32_f16(a, b, c, 0, 0, 0)
#define MFMA32(a, b, c) __builtin_amdgcn_mfma_f32_32x32x16_f16(a, b, c, 0, 0, 0)

__device__ inline void load_lds16(const void* g, void* l) {
  __builtin_amdgcn_global_load_lds(
      (const __attribute__((address_space(1))) unsigned int*)g,
      (__attribute__((address_space(3))) unsigned int*)l, 16, 0, 0);
}

__device__ inline unsigned pkrtz(float a, float b) {
  auto t = __builtin_amdgcn_cvt_pkrtz(a, b);
  return __builtin_bit_cast(unsigned, t);
}

// ---------------- pack kernels (fp32 -> fp16, concat layouts) ----------------

__global__ void pack_x_kernel(const float* __restrict__ xr, const float* __restrict__ xi,
                              f16* __restrict__ XC) {
  int i = blockIdx.x * 256 + threadIdx.x;
  if (i >= (4096 * 2048 / 4)) return;
  int idx = i * 4;
  int m = idx >> 11, k = idx & 2047;
  const float* src = (k < 1024) ? (xr + (size_t)m * 1024 + k) : (xi + (size_t)m * 1024 + k - 1024);
  float4 v = *(const float4*)src;
  f16x4 o = {(f16)v.x, (f16)v.y, (f16)v.z, (f16)v.w};
  *(f16x4*)(XC + idx) = o;
}

__global__ void pack_wqkv_kernel(const float* __restrict__ wr, const float* __restrict__ wi,
                                 f16* __restrict__ W) {
  int i = blockIdx.x * 256 + threadIdx.x;
  if (i >= (6144 * 2048 / 4)) return;
  int idx = i * 4;
  int n = idx >> 11, k = idx & 2047;
  const float* base;
  float sgn = 1.f;
  if (n < 3072) {
    if (k < 1024) base = wr + (size_t)n * 1024 + k;
    else { base = wi + (size_t)n * 1024 + k - 1024; sgn = -1.f; }
  } else {
    int n2 = n - 3072;
    if (k < 1024) base = wi + (size_t)n2 * 1024 + k;
    else base = wr + (size_t)n2 * 1024 + k - 1024;
  }
  float4 v = *(const float4*)base;
  f16x4 o = {(f16)(sgn * v.x), (f16)(sgn * v.y), (f16)(sgn * v.z), (f16)(sgn * v.w)};
  *(f16x4*)(W + idx) = o;
}

__global__ void pack_wout_kernel(const float* __restrict__ wor, const float* __restrict__ woi,
                                 f16* __restrict__ W) {
  int i = blockIdx.x * 256 + threadIdx.x;
  if (i >= (2048 * 2048 / 4)) return;
  int idx = i * 4;
  int n = idx >> 11, k = idx & 2047;
  const float* base;
  float sgn = 1.f;
  if (n < 1024) {
    if (k < 1024) base = wor + (size_t)n * 1024 + k;
    else { base = woi + (size_t)n * 1024 + k - 1024; sgn = -1.f; }
  } else {
    int n2 = n - 1024;
    if (k < 1024) base = woi + (size_t)n2 * 1024 + k;
    else base = wor + (size_t)n2 * 1024 + k - 1024;
  }
  float4 v = *(const float4*)base;
  f16x4 o = {(f16)(sgn * v.x), (f16)(sgn * v.y), (f16)(sgn * v.z), (f16)(sgn * v.w)};
  *(f16x4*)(W + idx) = o;
}

struct GemmParams {
  f16 *QC, *KCr, *KCi, *VCT;
  const float *bpr, *bpi;
  float* out;
  const float *bor, *boi;
  int out_complex;
};

// ---------------- GEMM1 (R15): 256x128 BK=32 dbuf, simple prefetch loop -------

__global__ __launch_bounds__(256, 3) void gemm1_kernel(const f16* __restrict__ A,
                                                       const f16* __restrict__ B,
                                                       GemmParams p) {
  const int K = 2048;
  __shared__ alignas(16) f16 sA[2][8192];
  __shared__ alignas(16) f16 sB[2][4096];
  const int tid = threadIdx.x;
  const int w = tid >> 6, l = tid & 63;
  const int lr = l & 15, lk = l >> 4;
  const int lin = blockIdx.x;
  const int xcd = lin & 7, idx = lin >> 3;
  const int mt = idx / 6, ntl = idx % 6;
  const int tm0 = mt * 256;
  const int tn0 = (xcd * 6 + ntl) * 128;
  const int wm = (w >> 1) * 128, wn = (w & 1) * 64;

  const int srow = tid >> 2;
  const int sk8 = ((tid & 3) ^ ((tid >> 3) & 3)) * 8;
  const f16* gA = A + (size_t)(tm0 + srow) * K + sk8;
  const f16* gB = B + (size_t)(tn0 + srow) * K + sk8;
  const int dst = w * 512;

#define STGA(buf, k0) do {                                                    \
    load_lds16(gA + (size_t)(k0), &sA[buf][dst]);                             \
    load_lds16(gA + (size_t)64 * K + (size_t)(k0), &sA[buf][2048 + dst]);     \
    load_lds16(gA + (size_t)128 * K + (size_t)(k0), &sA[buf][4096 + dst]);    \
    load_lds16(gA + (size_t)192 * K + (size_t)(k0), &sA[buf][6144 + dst]);    \
  } while (0)
#define STGB(buf, k0) do {                                                    \
    load_lds16(gB + (size_t)(k0), &sB[buf][dst]);                             \
    load_lds16(gB + (size_t)64 * K + (size_t)(k0), &sB[buf][2048 + dst]);     \
  } while (0)

  f32x4 acc[8][4] = {};

  STGA(0, 0);
  STGB(0, 0);
  asm volatile("s_waitcnt vmcnt(0)" ::: "memory");
  __syncthreads();

  const int ca = (lk ^ ((lr >> 1) & 3)) * 8;

  for (int t = 0; t < 64; ++t) {
    const int buf = t & 1;
    if (t < 63) {
      STGA(buf ^ 1, (t + 1) * 32);
      STGB(buf ^ 1, (t + 1) * 32);
    }
    const f16* pA = &sA[buf][0];
    const f16* pB = &sB[buf][0];
    f16x8 af[8], bf[4];
#pragma unroll
    for (int mi = 0; mi < 8; ++mi)
      af[mi] = *(const f16x8*)&pA[(wm + mi * 16 + lr) * 32 + ca];
#pragma unroll
    for (int nj = 0; nj < 4; ++nj)
      bf[nj] = *(const f16x8*)&pB[(wn + nj * 16 + lr) * 32 + ca];
#pragma unroll
    for (int mi = 0; mi < 8; ++mi)
#pragma unroll
      for (int nj = 0; nj < 4; ++nj)
        acc[mi][nj] = MFMA16(af[mi], bf[nj], acc[mi][nj]);
    asm volatile("s_waitcnt vmcnt(0)" ::: "memory");
    __syncthreads();
  }
#undef STGA
#undef STGB

#pragma unroll
  for (int mi = 0; mi < 8; ++mi)
#pragma unroll
    for (int nj = 0; nj < 4; ++nj) {
      int n = tn0 + wn + nj * 16 + lr;
      bool im = n >= 3072;
      int nn = im ? n - 3072 : n;
      float bias = im ? p.bpi[nn] : p.bpr[nn];
      int part = nn >> 10;
      int e = nn & 1023, h = e >> 6, dd = e & 63;
      int m0 = tm0 + wm + mi * 16 + lk * 4;
      int bb = m0 >> 10, s0 = m0 & 1023;
      size_t bh = (size_t)bb * 16 + h;
      if (part == 0) {
#pragma unroll
        for (int r = 0; r < 4; ++r)
          p.QC[(bh * 1024 + s0 + r) * 128 + (im ? 64 : 0) + dd] =
              (f16)((acc[mi][nj][r] + bias) * 0.125f);
      } else if (part == 1) {
#pragma unroll
        for (int r = 0; r < 4; ++r) {
          float v2 = acc[mi][nj][r] + bias;
          size_t o = (bh * 1024 + s0 + r) * 128;
          if (!im) { p.KCr[o + dd] = (f16)v2; p.KCi[o + 64 + dd] = (f16)v2; }
          else     { p.KCr[o + 64 + dd] = (f16)(-v2); p.KCi[o + dd] = (f16)v2; }
        }
      } else {
        f16x4 vv;
#pragma unroll
        for (int r = 0; r < 4; ++r) vv[r] = (f16)(acc[mi][nj][r] + bias);
        *(f16x4*)&p.VCT[((bh * 128 + (im ? 64 : 0) + dd)) * 1024 + s0] = vv;
      }
    }
}

// ---------------- GEMM2 (out proj): m97 128^2, proven 0-conflict --------------

__global__ __launch_bounds__(256) void gemm_out_kernel(const f16* __restrict__ A,
                                                       const f16* __restrict__ B,
                                                       GemmParams p) {
  const int K = 2048;
  __shared__ alignas(16) f16 sA[128 * 64];
  __shared__ alignas(16) f16 sB[128 * 64];
  const int tid = threadIdx.x;
  const int w = tid >> 6, l = tid & 63;
  const int lr = l & 15, lk = l >> 4;
  const int nwg = gridDim.x * gridDim.y;
  const int lin = blockIdx.y * gridDim.x + blockIdx.x;
  const int qq = nwg >> 3, rr = nwg & 7;
  const int xcd = lin & 7, off = lin >> 3;
  const int swz = (xcd < rr ? xcd * (qq + 1) : rr * (qq + 1) + (xcd - rr) * qq) + off;
  const int tm0 = (swz / gridDim.x) * 128;
  const int tn0 = (swz % gridDim.x) * 128;
  const int wm = (w >> 1) * 64, wn = (w & 1) * 64;

  f32x4 acc[4][4] = {};

  for (int k0 = 0; k0 < K; k0 += 64) {
#pragma unroll
    for (int i = 0; i < 4; ++i) {
      int slot = i * 256 + tid;
      int row = slot >> 3;
      int cg = (slot & 7) ^ (row & 7);
      load_lds16(A + (size_t)(tm0 + row) * K + k0 + cg * 8, &sA[(size_t)(i * 256 + (w << 6)) * 8]);
      load_lds16(B + (size_t)(tn0 + row) * K + k0 + cg * 8, &sB[(size_t)(i * 256 + (w << 6)) * 8]);
    }
    __syncthreads();
#pragma unroll
    for (int kk = 0; kk < 2; ++kk) {
      f16x8 af[4], bf[4];
#pragma unroll
      for (int t = 0; t < 4; ++t) {
        int rowA = wm + t * 16 + lr;
        af[t] = *(const f16x8*)&sA[rowA * 64 + ((kk * 4 + lk) ^ (rowA & 7)) * 8];
        int rowB = wn + t * 16 + lr;
        bf[t] = *(const f16x8*)&sB[rowB * 64 + ((kk * 4 + lk) ^ (rowB & 7)) * 8];
      }
#pragma unroll
      for (int mt = 0; mt < 4; ++mt)
#pragma unroll
        for (int nt = 0; nt < 4; ++nt) acc[mt][nt] = MFMA16(af[mt], bf[nt], acc[mt][nt]);
    }
    __syncthreads();
  }

#pragma unroll
  for (int mt = 0; mt < 4; ++mt)
#pragma unroll
    for (int nt = 0; nt < 4; ++nt)
#pragma unroll
      for (int r = 0; r < 4; ++r) {
        int m = tm0 + wm + mt * 16 + lk * 4 + r;
        int n = tn0 + wn + nt * 16 + lr;
        float val = acc[mt][nt][r];
        if (n < 1024) {
          float v2 = val + p.bor[n];
          if (p.out_complex) p.out[((size_t)m * 1024 + n) * 2] = v2;
          else p.out[(size_t)m * 1024 + n] = v2;
        } else {
          if (p.out_complex) p.out[((size_t)m * 1024 + n - 1024) * 2 + 1] = val + p.boi[n - 1024];
        }
      }
}

// ---------------- flash complex attention (swapped-operand 32x32) -------------
// grid = 512 blocks (8 q-tiles per head, XCD-local), block = 4 waves, QBLK=128.
// 48KB LDS -> 2-3 blocks/CU co-resident (cross-block latency hiding).

__global__ __launch_bounds__(256, 2) void attn_kernel(const f16* __restrict__ QC,
                                                      const f16* __restrict__ KCr,
                                                      const f16* __restrict__ KCi,
                                                      const f16* __restrict__ VCT,
                                                      f16* __restrict__ OC) {
  __shared__ alignas(16) f16 sKr[2][32 * 128];
  __shared__ alignas(16) f16 sKi[2][32 * 128];
  __shared__ alignas(16) f16 sV[2][128 * 32];
  const int tid = threadIdx.x;
  const int w = tid >> 6, l = tid & 63;
  const int lq = l & 31, hi = l >> 5;
  // XCD locality: 8 q-tile blocks of a head share bid%8 (== bh%8)
  const int bid = blockIdx.x;
  const int xx = bid & 7, yy = bid >> 3;
  const int bh = xx + ((yy >> 3) << 3);
  const int qt = yy & 7;
  const int q0 = qt * 128 + w * 32;
  const f16* Qb = QC + (size_t)bh * 1024 * 128;
  const f16* Krb = KCr + (size_t)bh * 1024 * 128;
  const f16* Kib = KCi + (size_t)bh * 1024 * 128;
  const f16* Vb = VCT + (size_t)bh * 128 * 1024;

  f16x8 qf[8];
#pragma unroll
  for (int c = 0; c < 8; ++c)
    qf[c] = *(const f16x8*)&Qb[(size_t)(q0 + lq) * 128 + c * 16 + hi * 8];

  f32x16 accR[4] = {};
  f32x16 accI[4] = {};
  float m_r = -1e30f, l_r = 0.f, m_i = -1e30f, l_i = 0.f;

  // staging (256 threads -> each array staged in 2 calls of 4KB)
  const int sprow = tid >> 3;                 // 0..31
  const int cK = (tid & 7) ^ ((tid >> 4) & 7);
  const f16* gKr = Krb + (size_t)(tid >> 4) * 128 + ((tid >> 3) & 1) * 64 + cK * 8;
  const f16* gKi = Kib + (size_t)(tid >> 4) * 128 + ((tid >> 3) & 1) * 64 + cK * 8;
  const int cV = (tid & 7) ^ (sprow & 7);
  const f16* gV = Vb + (size_t)(sprow * 2 + (cV >> 2)) * 1024 + (cV & 3) * 8;
  const int ldsW = w * 512;                   // wave piece within each 2048-f16 call region

#define STAGE(s, k0)                                                      \
  do {                                                                    \
    load_lds16(gKr + (size_t)(k0) * 128, &sKr[s][ldsW]);                  \
    load_lds16(gKr + (size_t)(k0) * 128 + 16 * 128, &sKr[s][2048 + ldsW]);\
    load_lds16(gKi + (size_t)(k0) * 128, &sKi[s][ldsW]);                  \
    load_lds16(gKi + (size_t)(k0) * 128 + 16 * 128, &sKi[s][2048 + ldsW]);\
    load_lds16(gV + (size_t)(k0), &sV[s][ldsW]);                          \
    load_lds16(gV + (size_t)64 * 1024 + (size_t)(k0), &sV[s][2048 + ldsW]);\
  } while (0)

  STAGE(0, 0);
  asm volatile("s_waitcnt vmcnt(0)" ::: "memory");
  __syncthreads();
  int cur = 0;

  for (int t = 0; t < 32; ++t) {
    if (t < 31) STAGE(cur ^ 1, (t + 1) * 32);

    f32x16 sr = {}, si = {};
    __builtin_amdgcn_s_setprio(1);
#pragma unroll
    for (int c = 0; c < 8; ++c) {
      int fc = c * 2 + hi;
      int prow = lq * 2 + (fc >> 3);
      int swzc = (fc & 7) ^ (lq & 7);
      f16x8 kr = *(const f16x8*)&sKr[cur][prow * 64 + swzc * 8];
      f16x8 ki = *(const f16x8*)&sKi[cur][prow * 64 + swzc * 8];
      sr = MFMA32(kr, qf[c], sr);
      si = MFMA32(ki, qf[c], si);
    }
    __builtin_amdgcn_s_setprio(0);

    f16x8 prf[2], pif[2];
#pragma unroll
    for (int part = 0; part < 2; ++part) {
      const f32x16& s = part ? si : sr;
      float& m = part ? m_i : m_r;
      float& lsum = part ? l_i : l_r;
      f32x16* acc = part ? accI : accR;
      float vm = s[0];
#pragma unroll
      for (int j = 1; j < 16; ++j) vm = fmaxf(vm, s[j]);
      vm = fmaxf(vm, __shfl_xor(vm, 32));
      if (__any(vm > m + 8.f)) {
        float mn = fmaxf(m, vm);
        float sc = __expf(m - mn);
        lsum *= sc;
#pragma unroll
        for (int a = 0; a < 4; ++a)
#pragma unroll
          for (int j = 0; j < 16; ++j) acc[a][j] *= sc;
        m = mn;
      }
      float p[16];
      float ls = 0.f;
#pragma unroll
      for (int j = 0; j < 16; ++j) { p[j] = __expf(s[j] - m); ls += p[j]; }
      lsum += ls;
      unsigned a0 = pkrtz(p[0], p[1]), b0 = pkrtz(p[4], p[5]);
      unsigned a1 = pkrtz(p[2], p[3]), b1 = pkrtz(p[6], p[7]);
      unsigned a2 = pkrtz(p[8], p[9]), b2 = pkrtz(p[12], p[13]);
      unsigned a3 = pkrtz(p[10], p[11]), b3 = pkrtz(p[14], p[15]);
      asm("v_permlane32_swap_b32 %0, %1" : "+v"(a0), "+v"(b0));
      asm("v_permlane32_swap_b32 %0, %1" : "+v"(a1), "+v"(b1));
      asm("v_permlane32_swap_b32 %0, %1" : "+v"(a2), "+v"(b2));
      asm("v_permlane32_swap_b32 %0, %1" : "+v"(a3), "+v"(b3));
      union { unsigned u[4]; f16x8 v; } f0, f1;
      f0.u[0] = a0; f0.u[1] = a1; f0.u[2] = b0; f0.u[3] = b1;
      f1.u[0] = a2; f1.u[1] = a3; f1.u[2] = b2; f1.u[3] = b3;
      if (part) { pif[0] = f0.v; pif[1] = f1.v; }
      else      { prf[0] = f0.v; prf[1] = f1.v; }
    }

    __builtin_amdgcn_s_setprio(1);
#pragma unroll
    for (int ft = 0; ft < 4; ++ft) {
#pragma unroll
      for (int ks = 0; ks < 2; ++ks) {
        int feat = ft * 32 + lq;
        int prow = feat >> 1;
        int swzc = (((feat & 1) * 4 + ks * 2 + hi) ^ (prow & 7));
        f16x8 vf = *(const f16x8*)&sV[cur][prow * 64 + swzc * 8];
        accR[ft] = MFMA32(vf, prf[ks], accR[ft]);
        accI[ft] = MFMA32(vf, pif[ks], accI[ft]);
      }
    }
    __builtin_amdgcn_s_setprio(0);

    asm volatile("s_waitcnt vmcnt(0)" ::: "memory");
    __syncthreads();
    cur ^= 1;
  }
#undef STAGE

  float lr = l_r + __shfl_xor(l_r, 32);
  float li = l_i + __shfl_xor(l_i, 32);
  float ilr = 1.f / lr, ili = 1.f / li;
  const int bb = bh >> 4, h = bh & 15;
  const int q = q0 + lq;
  f16* rowp = OC + ((size_t)bb * 1024 + q) * 2048 + h * 64;
#pragma unroll
  for (int tt = 0; tt < 2; ++tt) {
#pragma unroll
    for (int g = 0; g < 4; ++g) {
      int d0 = tt * 32 + g * 8 + hi * 4;
      f16x4 ov, oiv;
#pragma unroll
      for (int j = 0; j < 4; ++j) {
        int rg = g * 4 + j;
        float orv = accR[tt][rg] * ilr - accI[tt + 2][rg] * ili;
        float oivv = accR[tt + 2][rg] * ilr + accI[tt][rg] * ili;
        ov[j] = (f16)orv;
        oiv[j] = (f16)oivv;
      }
      *(f16x4*)(rowp + d0) = ov;
      *(f16x4*)(rowp + 1024 + d0) = oiv;
    }
  }
}

// ---------------- launcher ----------------------------------------------------

extern "C" void kernel_launch(void* const* d_in, const int* in_sizes, int n_in,
                              void* d_out, int out_size, void* d_ws, size_t ws_size,
                              hipStream_t stream) {
  const float* xr = (const float*)d_in[0];
  const float* xi = (const float*)d_in[1];
  const float* wpr = (const float*)d_in[2];
  const float* wpi = (const float*)d_in[3];
  const float* bpr = (const float*)d_in[4];
  const float* bpi = (const float*)d_in[5];
  const float* wor = (const float*)d_in[6];
  const float* woi = (const float*)d_in[7];
  const float* bor = (const float*)d_in[8];
  const float* boi = (const float*)d_in[9];

  f16* ws = (f16*)d_ws;
  f16* XC = ws;                       // 4096*2048
  f16* WQKV = XC + 8388608;           // 6144*2048
  f16* QC = WQKV + 12582912;          // 64*1024*128
  f16* KCr = QC + 8388608;
  f16* KCi = KCr + 8388608;
  f16* VCT = KCi + 8388608;           // 64*128*1024
  f16* OC = VCT + 8388608;            // 4096*2048
  f16* WOUT = OC + 8388608;           // 2048*2048

  pack_x_kernel<<<8192, 256, 0, stream>>>(xr, xi, XC);
  pack_wqkv_kernel<<<12288, 256, 0, stream>>>(wpr, wpi, WQKV);
  pack_wout_kernel<<<4096, 256, 0, stream>>>(wor, woi, WOUT);

  GemmParams p1 = {};
  p1.QC = QC; p1.KCr = KCr; p1.KCi = KCi; p1.VCT = VCT;
  p1.bpr = bpr; p1.bpi = bpi;
  gemm1_kernel<<<768, 256, 0, stream>>>(XC, WQKV, p1);

  attn_kernel<<<512, 256, 0, stream>>>(QC, KCr, KCi, VCT, OC);

  GemmParams p2 = {};
  p2.out = (float*)d_out; p2.bor = bor; p2.boi = boi;
  p2.out_complex = (out_size == 8388608) ? 1 : 0;
  int ntilesN = p2.out_complex ? 16 : 8;
  gemm_out_kernel<<<dim3(ntilesN, 32), 256, 0, stream>>>(OC, WOUT, p2);
}

// Round 18
// 263.280 us; speedup vs baseline: 1.1301x; 1.0738x over previous
//
#include <hip/hip_runtime.h>

// Complex MHA, B=4 S=1024 E=1024 H=16 DH=64.
// pack(fp32->fp16) -> GEMM1 (Karatsuba 3-mult complex: block 128x64, wave 64x32,
// K=1024 BK=32 dbuf, in-register sum operands, scatter epilogue) -> flash
// complex attention (swapped 32x32, 4-wave) -> GEMM2 (m97 128^2, K-concat).

typedef _Float16 f16;
typedef _Float16 f16x8 __attribute__((ext_vector_type(8)));
typedef _Float16 f16x4 __attribute__((ext_vector_type(4)));
typedef float f32x4 __attribute__((ext_vector_type(4)));
typedef float f32x16 __attribute__((ext_vector_type(16)));

#define MFMA16(a, b, c) __builtin_amdgcn_mfma_f32_16x16x32_f16(a, b, c, 0, 0, 0)
#define MFMA32(a, b, c) __builtin_amdgcn_mfma_f32_32x32x16_f16(a, b, c, 0, 0, 0)

__device__ inline void load_lds16(const void* g, void* l) {
  __builtin_amdgcn_global_load_lds(
      (const __attribute__((address_space(1))) unsigned int*)g,
      (__attribute__((address_space(3))) unsigned int*)l, 16, 0, 0);
}

__device__ inline unsigned pkrtz(float a, float b) {
  auto t = __builtin_amdgcn_cvt_pkrtz(a, b);
  return __builtin_bit_cast(unsigned, t);
}

// ---------------- pack kernels (fp32 -> fp16, concat layouts) ----------------

__global__ void pack_x_kernel(const float* __restrict__ xr, const float* __restrict__ xi,
                              f16* __restrict__ XC) {
  int i = blockIdx.x * 256 + threadIdx.x;
  if (i >= (4096 * 2048 / 4)) return;
  int idx = i * 4;
  int m = idx >> 11, k = idx & 2047;
  const float* src = (k < 1024) ? (xr + (size_t)m * 1024 + k) : (xi + (size_t)m * 1024 + k - 1024);
  float4 v = *(const float4*)src;
  f16x4 o = {(f16)v.x, (f16)v.y, (f16)v.z, (f16)v.w};
  *(f16x4*)(XC + idx) = o;
}

// WQKV[3072][2048]: [Wr | -Wi] (imag half negated; Karatsuba uses it as U-operand)
__global__ void pack_wqkv_kernel(const float* __restrict__ wr, const float* __restrict__ wi,
                                 f16* __restrict__ W) {
  int i = blockIdx.x * 256 + threadIdx.x;
  if (i >= (3072 * 2048 / 4)) return;
  int idx = i * 4;
  int n = idx >> 11, k = idx & 2047;
  const float* base;
  float sgn = 1.f;
  if (k < 1024) base = wr + (size_t)n * 1024 + k;
  else { base = wi + (size_t)n * 1024 + k - 1024; sgn = -1.f; }
  float4 v = *(const float4*)base;
  f16x4 o = {(f16)(sgn * v.x), (f16)(sgn * v.y), (f16)(sgn * v.z), (f16)(sgn * v.w)};
  *(f16x4*)(W + idx) = o;
}

__global__ void pack_wout_kernel(const float* __restrict__ wor, const float* __restrict__ woi,
                                 f16* __restrict__ W) {
  int i = blockIdx.x * 256 + threadIdx.x;
  if (i >= (2048 * 2048 / 4)) return;
  int idx = i * 4;
  int n = idx >> 11, k = idx & 2047;
  const float* base;
  float sgn = 1.f;
  if (n < 1024) {
    if (k < 1024) base = wor + (size_t)n * 1024 + k;
    else { base = woi + (size_t)n * 1024 + k - 1024; sgn = -1.f; }
  } else {
    int n2 = n - 1024;
    if (k < 1024) base = woi + (size_t)n2 * 1024 + k;
    else base = wor + (size_t)n2 * 1024 + k - 1024;
  }
  float4 v = *(const float4*)base;
  f16x4 o = {(f16)(sgn * v.x), (f16)(sgn * v.y), (f16)(sgn * v.z), (f16)(sgn * v.w)};
  *(f16x4*)(W + idx) = o;
}

struct GemmParams {
  f16 *QC, *KCr, *KCi, *VCT;
  const float *bpr, *bpi;
  float* out;
  const float *bor, *boi;
  int out_complex;
};

// ---------------- GEMM1: Karatsuba complex, block 128x64, wave 64x32 ----------
// C[4096][3072] complex = X[4096][1024]c * W[3072][1024]c^T.
// T1 = xr*wr ; U = xi*(-wi) [stored negated] ; T3 = (xr+xi)*(wr+wi).
// Re = T1+U ; Im = T3-T1+U. Sum operands formed in registers (v_pk_add_f16).
// R15-proven dbuf loop + 64B-row 0-conflict layout.

__global__ __launch_bounds__(256, 3) void gemm1_kernel(const f16* __restrict__ A,
                                                       const f16* __restrict__ B,
                                                       GemmParams p) {
  const int KW = 2048;  // row stride of XC / WQKV
  __shared__ alignas(16) f16 sAr[2][4096];  // 128 rows x 32 f16 (64B rows)
  __shared__ alignas(16) f16 sAi[2][4096];
  __shared__ alignas(16) f16 sBr[2][2048];  // 64 rows x 32 f16
  __shared__ alignas(16) f16 sBu[2][2048];  // -wi tile
  const int tid = threadIdx.x;
  const int w = tid >> 6, l = tid & 63;
  const int lr = l & 15, lk = l >> 4;
  // grid 1536: xcd owns 6 n-tiles x 32 m-tiles (n-fastest)
  const int lin = blockIdx.x;
  const int xcd = lin & 7, idx = lin >> 3;
  const int mt = idx / 6, ntl = idx % 6;
  const int tm0 = mt * 128;
  const int tn0 = (xcd * 6 + ntl) * 64;
  const int wm = (w >> 1) * 64, wn = (w & 1) * 32;

  // staging: 16B unit covers row tid>>2, pos tid&3; chunk pre-swizzled
  const int srow = tid >> 2;
  const int sk8 = ((tid & 3) ^ ((tid >> 3) & 3)) * 8;
  const f16* gAr = A + (size_t)(tm0 + srow) * KW + sk8;          // xr
  const f16* gAi = A + (size_t)(tm0 + srow) * KW + 1024 + sk8;   // xi
  const f16* gBr = B + (size_t)(tn0 + srow) * KW + sk8;          // wr (64 rows)
  const f16* gBu = B + (size_t)(tn0 + srow) * KW + 1024 + sk8;   // -wi
  const int dst = w * 512;

#define STG(buf, k0) do {                                                  \
    load_lds16(gAr + (size_t)(k0), &sAr[buf][dst]);                        \
    load_lds16(gAr + (size_t)64 * KW + (size_t)(k0), &sAr[buf][2048 + dst]);\
    load_lds16(gAi + (size_t)(k0), &sAi[buf][dst]);                        \
    load_lds16(gAi + (size_t)64 * KW + (size_t)(k0), &sAi[buf][2048 + dst]);\
    load_lds16(gBr + (size_t)(k0), &sBr[buf][dst]);                        \
    load_lds16(gBu + (size_t)(k0), &sBu[buf][dst]);                        \
  } while (0)

  f32x4 a1[4][2] = {};  // T1
  f32x4 aU[4][2] = {};  // U
  f32x4 a3[4][2] = {};  // T3

  STG(0, 0);
  asm volatile("s_waitcnt vmcnt(0)" ::: "memory");
  __syncthreads();

  const int ca = (lk ^ ((lr >> 1) & 3)) * 8;

  for (int t = 0; t < 32; ++t) {
    const int buf = t & 1;
    if (t < 31) STG(buf ^ 1, (t + 1) * 32);
    f16x8 ar[4], ai[4], br[2], bu[2];
#pragma unroll
    for (int mi = 0; mi < 4; ++mi) {
      ar[mi] = *(const f16x8*)&sAr[buf][(wm + mi * 16 + lr) * 32 + ca];
      ai[mi] = *(const f16x8*)&sAi[buf][(wm + mi * 16 + lr) * 32 + ca];
    }
#pragma unroll
    for (int nj = 0; nj < 2; ++nj) {
      br[nj] = *(const f16x8*)&sBr[buf][(wn + nj * 16 + lr) * 32 + ca];
      bu[nj] = *(const f16x8*)&sBu[buf][(wn + nj * 16 + lr) * 32 + ca];
    }
    // T1 and U
#pragma unroll
    for (int mi = 0; mi < 4; ++mi)
#pragma unroll
      for (int nj = 0; nj < 2; ++nj) {
        a1[mi][nj] = MFMA16(ar[mi], br[nj], a1[mi][nj]);
        aU[mi][nj] = MFMA16(ai[mi], bu[nj], aU[mi][nj]);
      }
    // sum operands in-register: as = xr+xi ; bs = wr - (-wi) = wr+wi
#pragma unroll
    for (int mi = 0; mi < 4; ++mi) ar[mi] = ar[mi] + ai[mi];
#pragma unroll
    for (int nj = 0; nj < 2; ++nj) br[nj] = br[nj] - bu[nj];
#pragma unroll
    for (int mi = 0; mi < 4; ++mi)
#pragma unroll
      for (int nj = 0; nj < 2; ++nj)
        a3[mi][nj] = MFMA16(ar[mi], br[nj], a3[mi][nj]);
    asm volatile("s_waitcnt vmcnt(0)" ::: "memory");
    __syncthreads();
  }
#undef STG

  // ---- epilogue: Re = T1+U+bias_r, Im = T3-T1+U+bias_i; scatter ----
#pragma unroll
  for (int mi = 0; mi < 4; ++mi)
#pragma unroll
    for (int nj = 0; nj < 2; ++nj) {
      int n = tn0 + wn + nj * 16 + lr;
      float br_ = p.bpr[n], bi_ = p.bpi[n];
      int part = n >> 10;
      int e = n & 1023, h = e >> 6, dd = e & 63;
      int m0 = tm0 + wm + mi * 16 + lk * 4;
      int bb = m0 >> 10, s0 = m0 & 1023;
      size_t bh = (size_t)bb * 16 + h;
      f32x4 re = a1[mi][nj] + aU[mi][nj];
      f32x4 im = a3[mi][nj] - a1[mi][nj] + aU[mi][nj];
      if (part == 0) {
#pragma unroll
        for (int r = 0; r < 4; ++r) {
          size_t o = (bh * 1024 + s0 + r) * 128;
          p.QC[o + dd] = (f16)((re[r] + br_) * 0.125f);
          p.QC[o + 64 + dd] = (f16)((im[r] + bi_) * 0.125f);
        }
      } else if (part == 1) {
#pragma unroll
        for (int r = 0; r < 4; ++r) {
          float vr = re[r] + br_, vi = im[r] + bi_;
          size_t o = (bh * 1024 + s0 + r) * 128;
          p.KCr[o + dd] = (f16)vr; p.KCr[o + 64 + dd] = (f16)(-vi);
          p.KCi[o + dd] = (f16)vi; p.KCi[o + 64 + dd] = (f16)vr;
        }
      } else {
        f16x4 vvr, vvi;
#pragma unroll
        for (int r = 0; r < 4; ++r) { vvr[r] = (f16)(re[r] + br_); vvi[r] = (f16)(im[r] + bi_); }
        *(f16x4*)&p.VCT[((bh * 128 + dd)) * 1024 + s0] = vvr;
        *(f16x4*)&p.VCT[((bh * 128 + 64 + dd)) * 1024 + s0] = vvi;
      }
    }
}

// ---------------- GEMM2 (out proj): m97 128^2, proven 0-conflict --------------

__global__ __launch_bounds__(256) void gemm_out_kernel(const f16* __restrict__ A,
                                                       const f16* __restrict__ B,
                                                       GemmParams p) {
  const int K = 2048;
  __shared__ alignas(16) f16 sA[128 * 64];
  __shared__ alignas(16) f16 sB[128 * 64];
  const int tid = threadIdx.x;
  const int w = tid >> 6, l = tid & 63;
  const int lr = l & 15, lk = l >> 4;
  const int nwg = gridDim.x * gridDim.y;
  const int lin = blockIdx.y * gridDim.x + blockIdx.x;
  const int qq = nwg >> 3, rr = nwg & 7;
  const int xcd = lin & 7, off = lin >> 3;
  const int swz = (xcd < rr ? xcd * (qq + 1) : rr * (qq + 1) + (xcd - rr) * qq) + off;
  const int tm0 = (swz / gridDim.x) * 128;
  const int tn0 = (swz % gridDim.x) * 128;
  const int wm = (w >> 1) * 64, wn = (w & 1) * 64;

  f32x4 acc[4][4] = {};

  for (int k0 = 0; k0 < K; k0 += 64) {
#pragma unroll
    for (int i = 0; i < 4; ++i) {
      int slot = i * 256 + tid;
      int row = slot >> 3;
      int cg = (slot & 7) ^ (row & 7);
      load_lds16(A + (size_t)(tm0 + row) * K + k0 + cg * 8, &sA[(size_t)(i * 256 + (w << 6)) * 8]);
      load_lds16(B + (size_t)(tn0 + row) * K + k0 + cg * 8, &sB[(size_t)(i * 256 + (w << 6)) * 8]);
    }
    __syncthreads();
#pragma unroll
    for (int kk = 0; kk < 2; ++kk) {
      f16x8 af[4], bf[4];
#pragma unroll
      for (int t = 0; t < 4; ++t) {
        int rowA = wm + t * 16 + lr;
        af[t] = *(const f16x8*)&sA[rowA * 64 + ((kk * 4 + lk) ^ (rowA & 7)) * 8];
        int rowB = wn + t * 16 + lr;
        bf[t] = *(const f16x8*)&sB[rowB * 64 + ((kk * 4 + lk) ^ (rowB & 7)) * 8];
      }
#pragma unroll
      for (int mt = 0; mt < 4; ++mt)
#pragma unroll
        for (int nt = 0; nt < 4; ++nt) acc[mt][nt] = MFMA16(af[mt], bf[nt], acc[mt][nt]);
    }
    __syncthreads();
  }

#pragma unroll
  for (int mt = 0; mt < 4; ++mt)
#pragma unroll
    for (int nt = 0; nt < 4; ++nt)
#pragma unroll
      for (int r = 0; r < 4; ++r) {
        int m = tm0 + wm + mt * 16 + lk * 4 + r;
        int n = tn0 + wn + nt * 16 + lr;
        float val = acc[mt][nt][r];
        if (n < 1024) {
          float v2 = val + p.bor[n];
          if (p.out_complex) p.out[((size_t)m * 1024 + n) * 2] = v2;
          else p.out[(size_t)m * 1024 + n] = v2;
        } else {
          if (p.out_complex) p.out[((size_t)m * 1024 + n - 1024) * 2 + 1] = val + p.boi[n - 1024];
        }
      }
}

// ---------------- flash complex attention (swapped-operand 32x32) -------------
// grid = 512 blocks (8 q-tiles per head, XCD-local), block = 4 waves, QBLK=128.

__global__ __launch_bounds__(256, 2) void attn_kernel(const f16* __restrict__ QC,
                                                      const f16* __restrict__ KCr,
                                                      const f16* __restrict__ KCi,
                                                      const f16* __restrict__ VCT,
                                                      f16* __restrict__ OC) {
  __shared__ alignas(16) f16 sKr[2][32 * 128];
  __shared__ alignas(16) f16 sKi[2][32 * 128];
  __shared__ alignas(16) f16 sV[2][128 * 32];
  const int tid = threadIdx.x;
  const int w = tid >> 6, l = tid & 63;
  const int lq = l & 31, hi = l >> 5;
  const int bid = blockIdx.x;
  const int xx = bid & 7, yy = bid >> 3;
  const int bh = xx + ((yy >> 3) << 3);
  const int qt = yy & 7;
  const int q0 = qt * 128 + w * 32;
  const f16* Qb = QC + (size_t)bh * 1024 * 128;
  const f16* Krb = KCr + (size_t)bh * 1024 * 128;
  const f16* Kib = KCi + (size_t)bh * 1024 * 128;
  const f16* Vb = VCT + (size_t)bh * 128 * 1024;

  f16x8 qf[8];
#pragma unroll
  for (int c = 0; c < 8; ++c)
    qf[c] = *(const f16x8*)&Qb[(size_t)(q0 + lq) * 128 + c * 16 + hi * 8];

  f32x16 accR[4] = {};
  f32x16 accI[4] = {};
  float m_r = -1e30f, l_r = 0.f, m_i = -1e30f, l_i = 0.f;

  const int sprow = tid >> 3;
  const int cK = (tid & 7) ^ ((tid >> 4) & 7);
  const f16* gKr = Krb + (size_t)(tid >> 4) * 128 + ((tid >> 3) & 1) * 64 + cK * 8;
  const f16* gKi = Kib + (size_t)(tid >> 4) * 128 + ((tid >> 3) & 1) * 64 + cK * 8;
  const int cV = (tid & 7) ^ (sprow & 7);
  const f16* gV = Vb + (size_t)(sprow * 2 + (cV >> 2)) * 1024 + (cV & 3) * 8;
  const int ldsW = w * 512;

#define STAGE(s, k0)                                                      \
  do {                                                                    \
    load_lds16(gKr + (size_t)(k0) * 128, &sKr[s][ldsW]);                  \
    load_lds16(gKr + (size_t)(k0) * 128 + 16 * 128, &sKr[s][2048 + ldsW]);\
    load_lds16(gKi + (size_t)(k0) * 128, &sKi[s][ldsW]);                  \
    load_lds16(gKi + (size_t)(k0) * 128 + 16 * 128, &sKi[s][2048 + ldsW]);\
    load_lds16(gV + (size_t)(k0), &sV[s][ldsW]);                          \
    load_lds16(gV + (size_t)64 * 1024 + (size_t)(k0), &sV[s][2048 + ldsW]);\
  } while (0)

  STAGE(0, 0);
  asm volatile("s_waitcnt vmcnt(0)" ::: "memory");
  __syncthreads();
  int cur = 0;

  for (int t = 0; t < 32; ++t) {
    if (t < 31) STAGE(cur ^ 1, (t + 1) * 32);

    f32x16 sr = {}, si = {};
    __builtin_amdgcn_s_setprio(1);
#pragma unroll
    for (int c = 0; c < 8; ++c) {
      int fc = c * 2 + hi;
      int prow = lq * 2 + (fc >> 3);
      int swzc = (fc & 7) ^ (lq & 7);
      f16x8 kr = *(const f16x8*)&sKr[cur][prow * 64 + swzc * 8];
      f16x8 ki = *(const f16x8*)&sKi[cur][prow * 64 + swzc * 8];
      sr = MFMA32(kr, qf[c], sr);
      si = MFMA32(ki, qf[c], si);
    }
    __builtin_amdgcn_s_setprio(0);

    f16x8 prf[2], pif[2];
#pragma unroll
    for (int part = 0; part < 2; ++part) {
      const f32x16& s = part ? si : sr;
      float& m = part ? m_i : m_r;
      float& lsum = part ? l_i : l_r;
      f32x16* acc = part ? accI : accR;
      float vm = s[0];
#pragma unroll
      for (int j = 1; j < 16; ++j) vm = fmaxf(vm, s[j]);
      vm = fmaxf(vm, __shfl_xor(vm, 32));
      if (__any(vm > m + 8.f)) {
        float mn = fmaxf(m, vm);
        float sc = __expf(m - mn);
        lsum *= sc;
#pragma unroll
        for (int a = 0; a < 4; ++a)
#pragma unroll
          for (int j = 0; j < 16; ++j) acc[a][j] *= sc;
        m = mn;
      }
      float p[16];
      float ls = 0.f;
#pragma unroll
      for (int j = 0; j < 16; ++j) { p[j] = __expf(s[j] - m); ls += p[j]; }
      lsum += ls;
      unsigned a0 = pkrtz(p[0], p[1]), b0 = pkrtz(p[4], p[5]);
      unsigned a1 = pkrtz(p[2], p[3]), b1 = pkrtz(p[6], p[7]);
      unsigned a2 = pkrtz(p[8], p[9]), b2 = pkrtz(p[12], p[13]);
      unsigned a3 = pkrtz(p[10], p[11]), b3 = pkrtz(p[14], p[15]);
      asm("v_permlane32_swap_b32 %0, %1" : "+v"(a0), "+v"(b0));
      asm("v_permlane32_swap_b32 %0, %1" : "+v"(a1), "+v"(b1));
      asm("v_permlane32_swap_b32 %0, %1" : "+v"(a2), "+v"(b2));
      asm("v_permlane32_swap_b32 %0, %1" : "+v"(a3), "+v"(b3));
      union { unsigned u[4]; f16x8 v; } f0, f1;
      f0.u[0] = a0; f0.u[1] = a1; f0.u[2] = b0; f0.u[3] = b1;
      f1.u[0] = a2; f1.u[1] = a3; f1.u[2] = b2; f1.u[3] = b3;
      if (part) { pif[0] = f0.v; pif[1] = f1.v; }
      else      { prf[0] = f0.v; prf[1] = f1.v; }
    }

    __builtin_amdgcn_s_setprio(1);
#pragma unroll
    for (int ft = 0; ft < 4; ++ft) {
#pragma unroll
      for (int ks = 0; ks < 2; ++ks) {
        int feat = ft * 32 + lq;
        int prow = feat >> 1;
        int swzc = (((feat & 1) * 4 + ks * 2 + hi) ^ (prow & 7));
        f16x8 vf = *(const f16x8*)&sV[cur][prow * 64 + swzc * 8];
        accR[ft] = MFMA32(vf, prf[ks], accR[ft]);
        accI[ft] = MFMA32(vf, pif[ks], accI[ft]);
      }
    }
    __builtin_amdgcn_s_setprio(0);

    asm volatile("s_waitcnt vmcnt(0)" ::: "memory");
    __syncthreads();
    cur ^= 1;
  }
#undef STAGE

  float lr = l_r + __shfl_xor(l_r, 32);
  float li = l_i + __shfl_xor(l_i, 32);
  float ilr = 1.f / lr, ili = 1.f / li;
  const int bb = bh >> 4, h = bh & 15;
  const int q = q0 + lq;
  f16* rowp = OC + ((size_t)bb * 1024 + q) * 2048 + h * 64;
#pragma unroll
  for (int tt = 0; tt < 2; ++tt) {
#pragma unroll
    for (int g = 0; g < 4; ++g) {
      int d0 = tt * 32 + g * 8 + hi * 4;
      f16x4 ov, oiv;
#pragma unroll
      for (int j = 0; j < 4; ++j) {
        int rg = g * 4 + j;
        float orv = accR[tt][rg] * ilr - accI[tt + 2][rg] * ili;
        float oivv = accR[tt + 2][rg] * ilr + accI[tt][rg] * ili;
        ov[j] = (f16)orv;
        oiv[j] = (f16)oivv;
      }
      *(f16x4*)(rowp + d0) = ov;
      *(f16x4*)(rowp + 1024 + d0) = oiv;
    }
  }
}

// ---------------- launcher ----------------------------------------------------

extern "C" void kernel_launch(void* const* d_in, const int* in_sizes, int n_in,
                              void* d_out, int out_size, void* d_ws, size_t ws_size,
                              hipStream_t stream) {
  const float* xr = (const float*)d_in[0];
  const float* xi = (const float*)d_in[1];
  const float* wpr = (const float*)d_in[2];
  const float* wpi = (const float*)d_in[3];
  const float* bpr = (const float*)d_in[4];
  const float* bpi = (const float*)d_in[5];
  const float* wor = (const float*)d_in[6];
  const float* woi = (const float*)d_in[7];
  const float* bor = (const float*)d_in[8];
  const float* boi = (const float*)d_in[9];

  f16* ws = (f16*)d_ws;
  f16* XC = ws;                       // 4096*2048
  f16* WQKV = XC + 8388608;           // 3072*2048
  f16* QC = WQKV + 6291456;           // 64*1024*128
  f16* KCr = QC + 8388608;
  f16* KCi = KCr + 8388608;
  f16* VCT = KCi + 8388608;           // 64*128*1024
  f16* OC = VCT + 8388608;            // 4096*2048
  f16* WOUT = OC + 8388608;           // 2048*2048

  pack_x_kernel<<<8192, 256, 0, stream>>>(xr, xi, XC);
  pack_wqkv_kernel<<<6144, 256, 0, stream>>>(wpr, wpi, WQKV);
  pack_wout_kernel<<<4096, 256, 0, stream>>>(wor, woi, WOUT);

  GemmParams p1 = {};
  p1.QC = QC; p1.KCr = KCr; p1.KCi = KCi; p1.VCT = VCT;
  p1.bpr = bpr; p1.bpi = bpi;
  // 8 XCD x (32 m-tiles of 128 x 6 n-tiles of 64) = 1536 blocks
  gemm1_kernel<<<1536, 256, 0, stream>>>(XC, WQKV, p1);

  attn_kernel<<<512, 256, 0, stream>>>(QC, KCr, KCi, VCT, OC);

  GemmParams p2 = {};
  p2.out = (float*)d_out; p2.bor = bor; p2.boi = boi;
  p2.out_complex = (out_size == 8388608) ? 1 : 0;
  int ntilesN = p2.out_complex ? 16 : 8;
  gemm_out_kernel<<<dim3(ntilesN, 32), 256, 0, stream>>>(OC, WOUT, p2);
}